// Round 3
// baseline (1523.624 us; speedup 1.0000x reference)
//
#include <hip/hip_runtime.h>
#include <cstdint>
#include <cstddef>

using short8  = __attribute__((ext_vector_type(8))) short;
using floatx4 = __attribute__((ext_vector_type(4))) float;
typedef unsigned short u16;

constexpr int NN = 30000;   // nodes
constexpr int NE = 60000;   // edges / messages
constexpr int BATCH = 256;
constexpr int VV = 40;
constexpr int NBOND = 4;
constexpr int TT = 6;
constexpr int PT = 1536, PA = 1280, PB = 2560;

__device__ __forceinline__ float b2f(u16 h) {
  union { unsigned u; float f; } v; v.u = ((unsigned)h) << 16; return v.f;
}
__device__ __forceinline__ u16 f2b(float f) {
  union { float f; unsigned u; } v; v.f = f;
  unsigned r = v.u + 0x7FFFu + ((v.u >> 16) & 1u);
  return (u16)(r >> 16);
}
__device__ __forceinline__ float lo16(unsigned u) {
  union { unsigned x; float f; } v; v.x = u << 16; return v.f;
}
__device__ __forceinline__ float hi16(unsigned u) {
  union { unsigned x; float f; } v; v.x = u & 0xffff0000u; return v.f;
}
__device__ __forceinline__ unsigned pack2(float a, float b) {
  return ((unsigned)f2b(a)) | (((unsigned)f2b(b)) << 16);
}

// ---------------------------------------------------------------------------
// Generic bf16 MFMA GEMM:  C[M,256] = epilogue(A[M,K] @ B[K,256])
// A row-major (bf16, or f32 when AF32), Bt = B^T row-major bf16 [256,K].
// 128x128 tile per block, 4 waves in 2x2, 16x16x32 MFMA, BK=32.
// ---------------------------------------------------------------------------
template<int RELU_BIAS, int AF32>
__global__ __launch_bounds__(256) void gemm_bt_kernel(
    const void* __restrict__ Av, int lda, int M,
    const u16* __restrict__ Bt, int K,
    u16* __restrict__ C, int ldc, const float* __restrict__ bias)
{
  __shared__ __align__(16) u16 As[128][56];
  __shared__ __align__(16) u16 Bs[128][56];
  const int tid  = threadIdx.x;
  const int wave = tid >> 6, lane = tid & 63;
  const int wm = wave >> 1, wn = wave & 1;
  const int lr = lane & 15, lk = (lane >> 4) * 8;
  const long rowbase = (long)blockIdx.x * 128;
  const int  colbase = blockIdx.y * 128;

  floatx4 acc[4][4];
#pragma unroll
  for (int i = 0; i < 4; i++)
#pragma unroll
    for (int j = 0; j < 4; j++) acc[i][j] = {0.f, 0.f, 0.f, 0.f};

  for (int k0 = 0; k0 < K; k0 += 32) {
#pragma unroll
    for (int r = 0; r < 2; r++) {
      int c = tid + 256 * r;
      int row = c >> 2, cc = (c & 3) * 8;
      long grow = rowbase + row;
      uint4 av = {0u, 0u, 0u, 0u};
      if (AF32) {
        if (grow < M) {
          const float* Af = (const float*)Av;
          float4 f0 = *(const float4*)(Af + grow * (long)lda + k0 + cc);
          float4 f1 = *(const float4*)(Af + grow * (long)lda + k0 + cc + 4);
          av.x = pack2(f0.x, f0.y); av.y = pack2(f0.z, f0.w);
          av.z = pack2(f1.x, f1.y); av.w = pack2(f1.z, f1.w);
        }
      } else {
        if (grow < M) av = *(const uint4*)((const u16*)Av + grow * (long)lda + k0 + cc);
      }
      *(uint4*)(&As[row][cc]) = av;
      uint4 bv = *(const uint4*)(Bt + (long)(colbase + row) * K + k0 + cc);
      *(uint4*)(&Bs[row][cc]) = bv;
    }
    __syncthreads();
    short8 af[4], bf[4];
#pragma unroll
    for (int mt = 0; mt < 4; mt++) af[mt] = *(const short8*)(&As[wm * 64 + mt * 16 + lr][lk]);
#pragma unroll
    for (int nt = 0; nt < 4; nt++) bf[nt] = *(const short8*)(&Bs[wn * 64 + nt * 16 + lr][lk]);
#pragma unroll
    for (int mt = 0; mt < 4; mt++)
#pragma unroll
      for (int nt = 0; nt < 4; nt++)
        acc[mt][nt] = __builtin_amdgcn_mfma_f32_16x16x32_bf16(af[mt], bf[nt], acc[mt][nt], 0, 0, 0);
    __syncthreads();
  }

  const int rq = (lane >> 4) * 4;
#pragma unroll
  for (int mt = 0; mt < 4; mt++) {
#pragma unroll
    for (int nt = 0; nt < 4; nt++) {
      int gcol = colbase + wn * 64 + nt * 16 + lr;
#pragma unroll
      for (int r2 = 0; r2 < 4; r2++) {
        long grow = rowbase + wm * 64 + mt * 16 + rq + r2;
        if (grow < M) {
          float v = acc[mt][nt][r2];
          if (RELU_BIAS) { v += bias[gcol]; v = v > 0.f ? v : 0.f; }
          C[grow * (long)ldc + gcol] = f2b(v);
        }
      }
    }
  }
}

// ---------------------------------------------------------------------------
// Merged topo+atom head GEMM: A = tva [(PT+PA) x 544]; blocks with
// rowbase < PT use (Bt1,b1), else (Bt2,b2). Always relu+bias. K=544, N=256.
// ---------------------------------------------------------------------------
__global__ __launch_bounds__(256) void gemm_ta_kernel(
    const u16* __restrict__ A,
    const u16* __restrict__ Bt1, const u16* __restrict__ Bt2,
    const float* __restrict__ b1, const float* __restrict__ b2,
    u16* __restrict__ C)
{
  constexpr int K = 544;
  __shared__ __align__(16) u16 As[128][56];
  __shared__ __align__(16) u16 Bs[128][56];
  const int tid  = threadIdx.x;
  const int wave = tid >> 6, lane = tid & 63;
  const int wm = wave >> 1, wn = wave & 1;
  const int lr = lane & 15, lk = (lane >> 4) * 8;
  const long rowbase = (long)blockIdx.x * 128;
  const int  colbase = blockIdx.y * 128;
  const u16* Bt = (rowbase < PT) ? Bt1 : Bt2;
  const float* bias = (rowbase < PT) ? b1 : b2;

  floatx4 acc[4][4];
#pragma unroll
  for (int i = 0; i < 4; i++)
#pragma unroll
    for (int j = 0; j < 4; j++) acc[i][j] = {0.f, 0.f, 0.f, 0.f};

  for (int k0 = 0; k0 < K; k0 += 32) {
#pragma unroll
    for (int r = 0; r < 2; r++) {
      int c = tid + 256 * r;
      int row = c >> 2, cc = (c & 3) * 8;
      long grow = rowbase + row;
      uint4 av = *(const uint4*)(A + grow * (long)K + k0 + cc);
      *(uint4*)(&As[row][cc]) = av;
      uint4 bv = *(const uint4*)(Bt + (long)(colbase + row) * K + k0 + cc);
      *(uint4*)(&Bs[row][cc]) = bv;
    }
    __syncthreads();
    short8 af[4], bf[4];
#pragma unroll
    for (int mt = 0; mt < 4; mt++) af[mt] = *(const short8*)(&As[wm * 64 + mt * 16 + lr][lk]);
#pragma unroll
    for (int nt = 0; nt < 4; nt++) bf[nt] = *(const short8*)(&Bs[wn * 64 + nt * 16 + lr][lk]);
#pragma unroll
    for (int mt = 0; mt < 4; mt++)
#pragma unroll
      for (int nt = 0; nt < 4; nt++)
        acc[mt][nt] = __builtin_amdgcn_mfma_f32_16x16x32_bf16(af[mt], bf[nt], acc[mt][nt], 0, 0, 0);
    __syncthreads();
  }

  const int rq = (lane >> 4) * 4;
#pragma unroll
  for (int mt = 0; mt < 4; mt++) {
#pragma unroll
    for (int nt = 0; nt < 4; nt++) {
      int gcol = colbase + wn * 64 + nt * 16 + lr;
#pragma unroll
      for (int r2 = 0; r2 < 4; r2++) {
        long grow = rowbase + wm * 64 + mt * 16 + rq + r2;
        float v = acc[mt][nt][r2] + bias[gcol];
        v = v > 0.f ? v : 0.f;
        C[grow * 256 + gcol] = f2b(v);
      }
    }
  }
}

// ---------------------------------------------------------------------------
// Fused gather + GEMM over the depth chain:
//   C[r,:] = A(r) @ B,  A(r) = relu(pre[e_r] + sum_j tab[lidx(r,j)] + b_h) * pad
// r in [0, Mtot), t_r = r/NE, e_r = r%NE; lidx = idx6[r*6+j] + t_r*tsrows.
// Tile: 128 rows x 256 cols, 512 threads (8 waves, 2x4), BK=32, K=256.
// ---------------------------------------------------------------------------
__global__ __launch_bounds__(512) void fused_gg_kernel(
    const u16* __restrict__ tab, int tsrows,
    const u16* __restrict__ pre, const float* __restrict__ bias,
    const int* __restrict__ idx6, int Mtot,
    const u16* __restrict__ Bt,   // [256][256] bf16 (B^T row-major)
    u16* __restrict__ C)
{
  __shared__ __align__(16) u16 As[128][40];
  __shared__ __align__(16) u16 Bs[256][40];
  __shared__ int sidx[128][6];
  __shared__ int spre[128];   // e_r (>0), or -1 for pad/out-of-range
  const int tid = threadIdx.x;
  const int rowbase = blockIdx.x * 128;

  for (int i = tid; i < 128 * 6; i += 512) {
    int r = i / 6, j = i - r * 6;
    int grow = rowbase + r;
    int v = 0;
    if (grow < Mtot) {
      int t_r = grow / NE;
      v = idx6[(long)grow * 6 + j] + t_r * tsrows;
    }
    sidx[r][j] = v;
  }
  if (tid < 128) {
    int grow = rowbase + tid;
    int e = -1;
    if (grow < Mtot) {
      int t_r = grow / NE;
      e = grow - t_r * NE;
      if (e == 0) e = -1;
    }
    spre[tid] = e;
  }
  __syncthreads();

  const int wave = tid >> 6, lane = tid & 63;
  const int wm = wave >> 2, wn = wave & 3;
  const int lr = lane & 15, lk = (lane >> 4) * 8;
  const int arow = tid >> 2, acc8 = (tid & 3) * 8;   // A staging: 128 rows x 4 chunks
  const int brow = tid >> 1, bc16 = (tid & 1) * 16;  // B staging: 256 rows x 2 chunks

  floatx4 acc[4][4];
#pragma unroll
  for (int i = 0; i < 4; i++)
#pragma unroll
    for (int j = 0; j < 4; j++) acc[i][j] = {0.f, 0.f, 0.f, 0.f};

  for (int k0 = 0; k0 < 256; k0 += 32) {
    // --- stage A (fused gather) ---
    {
      int e = spre[arow];
      float a0 = 0.f, a1 = 0.f, a2 = 0.f, a3 = 0.f, a4 = 0.f, a5 = 0.f, a6 = 0.f, a7 = 0.f;
      if (e >= 0) {
        uint4 p = *(const uint4*)(pre + (long)e * 256 + k0 + acc8);
        a0 = lo16(p.x); a1 = hi16(p.x); a2 = lo16(p.y); a3 = hi16(p.y);
        a4 = lo16(p.z); a5 = hi16(p.z); a6 = lo16(p.w); a7 = hi16(p.w);
#pragma unroll
        for (int j = 0; j < 6; j++) {
          uint4 g = *(const uint4*)(tab + (long)sidx[arow][j] * 256 + k0 + acc8);
          a0 += lo16(g.x); a1 += hi16(g.x); a2 += lo16(g.y); a3 += hi16(g.y);
          a4 += lo16(g.z); a5 += hi16(g.z); a6 += lo16(g.w); a7 += hi16(g.w);
        }
        float4 b0 = *(const float4*)(bias + k0 + acc8);
        float4 b1 = *(const float4*)(bias + k0 + acc8 + 4);
        a0 = fmaxf(a0 + b0.x, 0.f); a1 = fmaxf(a1 + b0.y, 0.f);
        a2 = fmaxf(a2 + b0.z, 0.f); a3 = fmaxf(a3 + b0.w, 0.f);
        a4 = fmaxf(a4 + b1.x, 0.f); a5 = fmaxf(a5 + b1.y, 0.f);
        a6 = fmaxf(a6 + b1.z, 0.f); a7 = fmaxf(a7 + b1.w, 0.f);
      }
      uint4 o; o.x = pack2(a0, a1); o.y = pack2(a2, a3); o.z = pack2(a4, a5); o.w = pack2(a6, a7);
      *(uint4*)(&As[arow][acc8]) = o;
      // --- stage B ---
      uint4 v0 = *(const uint4*)(Bt + (long)brow * 256 + k0 + bc16);
      uint4 v1 = *(const uint4*)(Bt + (long)brow * 256 + k0 + bc16 + 8);
      *(uint4*)(&Bs[brow][bc16]) = v0;
      *(uint4*)(&Bs[brow][bc16 + 8]) = v1;
    }
    __syncthreads();
    short8 af[4], bf[4];
#pragma unroll
    for (int mt = 0; mt < 4; mt++) af[mt] = *(const short8*)(&As[wm * 64 + mt * 16 + lr][lk]);
#pragma unroll
    for (int nt = 0; nt < 4; nt++) bf[nt] = *(const short8*)(&Bs[wn * 64 + nt * 16 + lr][lk]);
#pragma unroll
    for (int mt = 0; mt < 4; mt++)
#pragma unroll
      for (int nt = 0; nt < 4; nt++)
        acc[mt][nt] = __builtin_amdgcn_mfma_f32_16x16x32_bf16(af[mt], bf[nt], acc[mt][nt], 0, 0, 0);
    __syncthreads();
  }

  const int rq = (lane >> 4) * 4;
#pragma unroll
  for (int mt = 0; mt < 4; mt++) {
#pragma unroll
    for (int nt = 0; nt < 4; nt++) {
      int gcol = wn * 64 + nt * 16 + lr;
#pragma unroll
      for (int r2 = 0; r2 < 4; r2++) {
        long grow = (long)rowbase + wm * 64 + mt * 16 + rq + r2;
        if (grow < Mtot) C[grow * 256 + gcol] = f2b(acc[mt][nt][r2]);
      }
    }
  }
}

// ---------------------------------------------------------------------------
// small utility kernels
// ---------------------------------------------------------------------------

// all 9 weight transposes in one dispatch. Bt[n][k]=bf16(W[k][n]), k>=K -> 0.
struct TW { const float* W; int K; int Kpad; u16* Bt; int blk0; };
__global__ __launch_bounds__(256) void transpose_all_kernel(
    const float* W_h, const float* U_h, const float* W_o,
    const float* tw1, const float* aw1, const float* bw1,
    const float* rw, const float* ww,
    u16* Wh_t, u16* Uh_t, u16* Wo1_t, u16* Wo2_t,
    u16* tw1_t, u16* aw1_t, u16* bw1_t, u16* rw_t, u16* ww_t)
{
  int b = blockIdx.x;
  const float* W; int K, Kpad; u16* Bt; int base;
  if      (b < 256)  { W = W_h;  K = 256; Kpad = 256; Bt = Wh_t;  base = 0; }
  else if (b < 512)  { W = U_h;  K = 256; Kpad = 256; Bt = Uh_t;  base = 256; }
  else if (b < 768)  { W = W_o;  K = 256; Kpad = 256; Bt = Wo1_t; base = 512; }
  else if (b < 1024) { W = W_o + 256 * 256; K = 256; Kpad = 256; Bt = Wo2_t; base = 768; }
  else if (b < 1568) { W = tw1;  K = 544; Kpad = 544; Bt = tw1_t; base = 1024; }
  else if (b < 2112) { W = aw1;  K = 544; Kpad = 544; Bt = aw1_t; base = 1568; }
  else if (b < 2912) { W = bw1;  K = 800; Kpad = 800; Bt = bw1_t; base = 2112; }
  else if (b < 3232) { W = rw;   K = 296; Kpad = 320; Bt = rw_t;  base = 2912; }
  else               { W = ww;   K = 260; Kpad = 288; Bt = ww_t;  base = 3232; }
  int idx = (b - base) * 256 + threadIdx.x;
  int n = idx / Kpad, k = idx - n * Kpad;
  Bt[idx] = (k < K) ? f2b(W[(long)k * 256 + n]) : (u16)0;
}

// masked neighbor lists for both graphs, all steps
__global__ __launch_bounds__(256) void mask_kernel(const int* __restrict__ bgraph,
                                                   const int* __restrict__ agraph,
                                                   const int* __restrict__ em,
                                                   int* __restrict__ bgm, int* __restrict__ agm)
{
  int t = blockIdx.y;
  const int* emt = em + (long)t * NE;
  if (blockIdx.x < 1407) {
    int i = blockIdx.x * 256 + threadIdx.x;
    if (i >= NE * 6) return;
    int v = bgraph[i];
    bgm[(long)t * NE * 6 + i] = v * emt[v];
  } else {
    int i = (blockIdx.x - 1407) * 256 + threadIdx.x;
    if (i >= NN * 6) return;
    int v = agraph[i];
    agm[(long)t * NN * 6 + i] = v * emt[v];
  }
}

// h1 = relu(pre + b_h) * pad
__global__ __launch_bounds__(256) void h1_kernel(const u16* __restrict__ pre,
                                                 const float* __restrict__ bh,
                                                 u16* __restrict__ out)
{
  long i = (long)blockIdx.x * 256 + threadIdx.x;
  if (i >= (long)NE * 64) return;
  int row = (int)(i >> 6);
  int c = ((int)i & 63) * 4;
  ushort4 p = *(const ushort4*)(pre + (long)row * 256 + c);
  float4 b = *(const float4*)(bh + c);
  float x0 = b2f(p.x) + b.x, x1 = b2f(p.y) + b.y, x2 = b2f(p.z) + b.z, x3 = b2f(p.w) + b.w;
  if (row == 0) { x0 = x1 = x2 = x3 = 0.f; }
  else { x0 = fmaxf(x0, 0.f); x1 = fmaxf(x1, 0.f); x2 = fmaxf(x2, 0.f); x3 = fmaxf(x3, 0.f); }
  ushort4 o; o.x = f2b(x0); o.y = f2b(x1); o.z = f2b(x2); o.w = f2b(x3);
  *(ushort4*)(out + (long)row * 256 + c) = o;
}

// node[t][n] = relu(fo[n] + sum_j tab[t*tsrows*256 + idx[t][n][j]*256] + b_o) * vm[t][n]
__global__ __launch_bounds__(256) void gather_n2_kernel(
    const u16* __restrict__ tab, long tstride, const u16* __restrict__ fo,
    const float* __restrict__ bias, const int* __restrict__ idx,
    const int* __restrict__ vm, u16* __restrict__ outp)
{
  constexpr int BPT = NN / 8;
  int t = blockIdx.x / BPT;
  int n0 = (blockIdx.x - t * BPT) * 8;
  __shared__ int sidx[8][6];
  __shared__ int svm[8];
  int tid = threadIdx.x;
  if (tid < 48) sidx[tid / 6][tid % 6] = idx[(long)t * NN * 6 + n0 * 6 + tid];
  if (tid >= 48 && tid < 56) svm[tid - 48] = vm[(long)t * NN + n0 + (tid - 48)];
  __syncthreads();
  int rl = tid >> 5;
  int ch = (tid & 31) * 8;
  int n = n0 + rl;
  const u16* tb = tab + (long)t * tstride;
  uint4 p = *(const uint4*)(fo + (long)n * 256 + ch);
  float a0 = lo16(p.x), a1 = hi16(p.x), a2 = lo16(p.y), a3 = hi16(p.y);
  float a4 = lo16(p.z), a5 = hi16(p.z), a6 = lo16(p.w), a7 = hi16(p.w);
#pragma unroll
  for (int j = 0; j < 6; j++) {
    uint4 g = *(const uint4*)(tb + (long)sidx[rl][j] * 256 + ch);
    a0 += lo16(g.x); a1 += hi16(g.x); a2 += lo16(g.y); a3 += hi16(g.y);
    a4 += lo16(g.z); a5 += hi16(g.z); a6 += lo16(g.w); a7 += hi16(g.w);
  }
  float4 b0 = *(const float4*)(bias + ch);
  float4 b1 = *(const float4*)(bias + ch + 4);
  a0 += b0.x; a1 += b0.y; a2 += b0.z; a3 += b0.w;
  a4 += b1.x; a5 += b1.y; a6 += b1.z; a7 += b1.w;
  a0 = fmaxf(a0, 0.f); a1 = fmaxf(a1, 0.f); a2 = fmaxf(a2, 0.f); a3 = fmaxf(a3, 0.f);
  a4 = fmaxf(a4, 0.f); a5 = fmaxf(a5, 0.f); a6 = fmaxf(a6, 0.f); a7 = fmaxf(a7, 0.f);
  if (svm[rl] == 0) { a0 = a1 = a2 = a3 = a4 = a5 = a6 = a7 = 0.f; }
  uint4 o; o.x = pack2(a0, a1); o.y = pack2(a2, a3); o.z = pack2(a4, a5); o.w = pack2(a6, a7);
  *(uint4*)(outp + ((long)t * NN + n) * 256 + ch) = o;
}

// segmented-sum graph vectors: 32 rows/block, atomic flush on segment change.
// gv must be pre-zeroed.
__global__ __launch_bounds__(256) void gvec_atomic_kernel(const u16* __restrict__ node,
                                                          const int* __restrict__ n2g,
                                                          float* __restrict__ gv, int t0)
{
  int tl = blockIdx.y;
  int r0 = blockIdx.x * 32;
  int h = threadIdx.x;
  const u16* nd = node + (long)tl * NN * 256;
  float* gb = gv + (long)(t0 + tl) * BATCH * 256;
  int rend = r0 + 32; if (rend > NN) rend = NN;
  int gprev = n2g[r0];
  float acc = 0.f;
  for (int r = r0; r < rend; r++) {
    int g = n2g[r];
    if (g != gprev) { atomicAdd(gb + gprev * 256 + h, acc); acc = 0.f; gprev = g; }
    acc += b2f(nd[(long)r * 256 + h]);
  }
  atomicAdd(gb + gprev * 256 + h, acc);
}

// scatter node rows with step in [t0, t0+TB) into head-input matrices
__global__ __launch_bounds__(256) void head_gather_kernel(int t0, int TB,
    const u16* __restrict__ node,
    const int* __restrict__ tstep, const int* __restrict__ txid,
    const int* __restrict__ astep, const int* __restrict__ axid,
    const int* __restrict__ bstep, const int* __restrict__ bzid,
    u16* __restrict__ tv, u16* __restrict__ av, u16* __restrict__ bv,
    u16* __restrict__ wbin)
{
  int wave = threadIdx.x >> 6, lane = threadIdx.x & 63;
  int r = blockIdx.x * 4 + wave;
  int c = lane * 4;
  if (r < PT) {
    int st = tstep[r];
    if (st < t0 || st >= t0 + TB) return;
    ushort4 v = *(const ushort4*)(node + ((long)(st - t0) * NN + txid[r]) * 256 + c);
    *(ushort4*)(tv + (long)r * 544 + 256 + c) = v;
  } else if (r < PT + PA) {
    int i = r - PT;
    int st = astep[i];
    if (st < t0 || st >= t0 + TB) return;
    ushort4 v = *(const ushort4*)(node + ((long)(st - t0) * NN + axid[i]) * 256 + c);
    *(ushort4*)(av + (long)i * 544 + 256 + c) = v;
  } else if (r < PT + PA + PB) {
    int i = r - PT - PA;
    int st = bstep[i];
    if (st < t0 || st >= t0 + TB) return;
    ushort4 v = *(const ushort4*)(node + ((long)(st - t0) * NN + bzid[i]) * 256 + c);
    *(ushort4*)(bv + (long)i * 800 + 512 + c) = v;
    *(ushort4*)(wbin + (long)i * 288 + c) = v;
  }
}

// fill gvec / src / one-hot segments of head inputs (after all steps)
__global__ __launch_bounds__(256) void build_static_kernel(
    const float* __restrict__ gvec, const float* __restrict__ src,
    const int* __restrict__ tstep, const int* __restrict__ tbid,
    const int* __restrict__ astep, const int* __restrict__ abid,
    const int* __restrict__ bstep, const int* __restrict__ bbid,
    const int* __restrict__ blabel, const int* __restrict__ batype,
    u16* __restrict__ tv, u16* __restrict__ av, u16* __restrict__ bv,
    u16* __restrict__ wbin, u16* __restrict__ rbin)
{
  int wave = threadIdx.x >> 6, lane = threadIdx.x & 63;
  int r = blockIdx.x * 4 + wave;
  int c = lane * 4;
  if (r < PT) {
    int st = tstep[r], bid = tbid[r];
    const float* g = gvec + ((long)st * BATCH + bid) * 256;
    u16* d = tv + (long)r * 544;
    float4 g4 = *(const float4*)(g + c);
    d[c] = f2b(g4.x); d[c + 1] = f2b(g4.y); d[c + 2] = f2b(g4.z); d[c + 3] = f2b(g4.w);
    if (lane < 8) {
      float4 s4 = *(const float4*)(src + bid * 32 + c);
      d[512 + c] = f2b(s4.x); d[512 + c + 1] = f2b(s4.y);
      d[512 + c + 2] = f2b(s4.z); d[512 + c + 3] = f2b(s4.w);
    }
  } else if (r < PT + PA) {
    int i = r - PT;
    int st = astep[i], bid = abid[i];
    const float* g = gvec + ((long)st * BATCH + bid) * 256;
    u16* d = av + (long)i * 544;
    float4 g4 = *(const float4*)(g + c);
    d[c] = f2b(g4.x); d[c + 1] = f2b(g4.y); d[c + 2] = f2b(g4.z); d[c + 3] = f2b(g4.w);
    if (lane < 8) {
      float4 s4 = *(const float4*)(src + bid * 32 + c);
      d[512 + c] = f2b(s4.x); d[512 + c + 1] = f2b(s4.y);
      d[512 + c + 2] = f2b(s4.z); d[512 + c + 3] = f2b(s4.w);
    }
  } else if (r < PT + PA + PB) {
    int i = r - PT - PA;
    int st = bstep[i], bid = bbid[i];
    const float* g = gvec + ((long)st * BATCH + bid) * 256;
    u16* d = bv + (long)i * 800;
    float4 g4 = *(const float4*)(g + c);
    d[c] = f2b(g4.x); d[c + 1] = f2b(g4.y); d[c + 2] = f2b(g4.z); d[c + 3] = f2b(g4.w);
    if (lane < 8) {
      float4 s4 = *(const float4*)(src + bid * 32 + c);
      d[768 + c] = f2b(s4.x); d[768 + c + 1] = f2b(s4.y);
      d[768 + c + 2] = f2b(s4.z); d[768 + c + 3] = f2b(s4.w);
      int bl = blabel[i];
      u16* wd = wbin + (long)i * 288 + 256;
      for (int q = 0; q < 4; q++) {
        int k = c + q;
        wd[k] = f2b((k < NBOND && bl == k) ? 1.f : 0.f);
      }
    }
    if (lane < 16) {
      int at = batype[i];
      u16* rd = rbin + (long)i * 320 + 256;
      for (int q = 0; q < 4; q++) {
        int k = c + q;
        rd[k] = f2b((k < VV && at == k) ? 1.f : 0.f);
      }
    }
  }
}

// rbin[r][0:256] = sum_{j in [gs[r], r)} wb[j] * (blabel[j] > 0)
__global__ __launch_bounds__(256) void hist_kernel(
    const u16* __restrict__ wb, const int* __restrict__ gs_arr,
    const int* __restrict__ blabel, u16* __restrict__ rbin)
{
  int wave = threadIdx.x >> 6, lane = threadIdx.x & 63;
  int r = blockIdx.x * 4 + wave;
  if (r >= PB) return;
  int c = lane * 4;
  float a0 = 0.f, a1 = 0.f, a2 = 0.f, a3 = 0.f;
  int gs = gs_arr[r];
  for (int j = gs; j < r; j++) {
    if (blabel[j] > 0) {
      ushort4 g = *(const ushort4*)(wb + (long)j * 256 + c);
      a0 += b2f(g.x); a1 += b2f(g.y); a2 += b2f(g.z); a3 += b2f(g.w);
    }
  }
  u16* rd = rbin + (long)r * 320;
  rd[c] = f2b(a0); rd[c + 1] = f2b(a1); rd[c + 2] = f2b(a2); rd[c + 3] = f2b(a3);
}

// topo: BCE-with-logits, one wave per row
__global__ __launch_bounds__(256) void topo_loss_kernel(
    const u16* __restrict__ hidden, const float* __restrict__ w2,
    const float* __restrict__ b2, const int* __restrict__ label,
    float* __restrict__ out)
{
  int wave = threadIdx.x >> 6, lane = threadIdx.x & 63;
  int r = blockIdx.x * 4 + wave;
  if (r >= PT) return;
  const u16* h = hidden + (long)r * 256;
  int c = lane * 4;
  ushort4 hv = *(const ushort4*)(h + c);
  float4 wv = *(const float4*)(w2 + c);
  float s = b2f(hv.x) * wv.x + b2f(hv.y) * wv.y + b2f(hv.z) * wv.z + b2f(hv.w) * wv.w;
#pragma unroll
  for (int off = 32; off > 0; off >>= 1) s += __shfl_xor(s, off);
  if (lane == 0) {
    float l = s + b2[0];
    float y = (float)label[r];
    float sp = fmaxf(l, 0.f) + log1pf(expf(-fabsf(l)));
    atomicAdd(out, (sp - l * y) * (1.0f / BATCH));
  }
}

// cross-entropy over NC classes (NC<=64): w2 in LDS, shuffle-broadcast h
template<int NC>
__global__ __launch_bounds__(256) void ce_loss_kernel(
    const u16* __restrict__ hidden, const float* __restrict__ w2,
    const float* __restrict__ b2, const int* __restrict__ label,
    int rows, float* __restrict__ out)
{
  __shared__ float w2s[256 * NC];
  for (int i = threadIdx.x; i < 256 * NC; i += 256) w2s[i] = w2[i];
  __syncthreads();
  int wave = threadIdx.x >> 6, lane = threadIdx.x & 63;
  int r = blockIdx.x * 4 + wave;
  if (r >= rows) return;
  const u16* h = hidden + (long)r * 256;
  ushort4 hv4 = *(const ushort4*)(h + lane * 4);
  float h0 = b2f(hv4.x), h1 = b2f(hv4.y), h2 = b2f(hv4.z), h3 = b2f(hv4.w);
  bool valid = lane < NC;
  float s = valid ? b2[lane] : 0.f;
#pragma unroll 8
  for (int j = 0; j < 64; j++) {
    float a0 = __shfl(h0, j), a1 = __shfl(h1, j), a2 = __shfl(h2, j), a3 = __shfl(h3, j);
    if (valid) {
      int c = j * 4;
      s += a0 * w2s[c * NC + lane] + a1 * w2s[(c + 1) * NC + lane]
         + a2 * w2s[(c + 2) * NC + lane] + a3 * w2s[(c + 3) * NC + lane];
    }
  }
  float logit = valid ? s : -1e30f;
  float m = logit;
#pragma unroll
  for (int off = 32; off > 0; off >>= 1) m = fmaxf(m, __shfl_xor(m, off));
  float e = valid ? expf(logit - m) : 0.f;
#pragma unroll
  for (int off = 32; off > 0; off >>= 1) e += __shfl_xor(e, off);
  float lse = m + logf(e);
  int lb = label[r];
  float ll = __shfl(logit, lb);
  if (lane == 0) atomicAdd(out, (lse - ll) * (1.0f / BATCH));
}

// ---------------------------------------------------------------------------
extern "C" void kernel_launch(void* const* d_in, const int* in_sizes, int n_in,
                              void* d_out, int out_size, void* d_ws, size_t ws_size,
                              hipStream_t stream)
{
  const float* src      = (const float*)d_in[0];
  const float* fnode    = (const float*)d_in[1];
  const float* fmess    = (const float*)d_in[2];
  const float* W_h      = (const float*)d_in[3];
  const float* U_h      = (const float*)d_in[4];
  const float* b_h      = (const float*)d_in[5];
  const float* W_o      = (const float*)d_in[6];
  const float* b_o      = (const float*)d_in[7];
  const float* topo_w1  = (const float*)d_in[8];
  const float* topo_b1  = (const float*)d_in[9];
  const float* topo_w2  = (const float*)d_in[10];
  const float* topo_b2  = (const float*)d_in[11];
  const float* atom_w1  = (const float*)d_in[12];
  const float* atom_b1  = (const float*)d_in[13];
  const float* atom_w2  = (const float*)d_in[14];
  const float* atom_b2  = (const float*)d_in[15];
  const float* bond_w1  = (const float*)d_in[16];
  const float* bond_b1  = (const float*)d_in[17];
  const float* bond_w2  = (const float*)d_in[18];
  const float* bond_b2  = (const float*)d_in[19];
  const float* rbond_w  = (const float*)d_in[20];
  const float* rbond_b  = (const float*)d_in[21];
  const float* wbond_w  = (const float*)d_in[22];
  const float* wbond_b  = (const float*)d_in[23];
  const int* agraph     = (const int*)d_in[24];
  const int* bgraph     = (const int*)d_in[25];
  const int* node2graph = (const int*)d_in[26];
  const int* emask      = (const int*)d_in[27];
  const int* vmask      = (const int*)d_in[28];
  const int* topo_step  = (const int*)d_in[29];
  const int* topo_bid   = (const int*)d_in[30];
  const int* topo_xid   = (const int*)d_in[31];
  const int* topo_label = (const int*)d_in[32];
  const int* atom_step  = (const int*)d_in[33];
  const int* atom_bid   = (const int*)d_in[34];
  const int* atom_xid   = (const int*)d_in[35];
  const int* atom_label = (const int*)d_in[36];
  const int* bond_step  = (const int*)d_in[37];
  const int* bond_bid   = (const int*)d_in[38];
  const int* bond_zid   = (const int*)d_in[39];
  const int* bond_atype = (const int*)d_in[40];
  const int* bond_label = (const int*)d_in[41];
  const int* bond_gs    = (const int*)d_in[42];

  char* wp = (char*)d_ws;
  auto alloc = [&](size_t bytes) -> char* {
    char* p = wp; wp += (bytes + 255) & ~(size_t)255; return p;
  };
  // fixed allocations
  u16* preB   = (u16*)alloc((size_t)NE * 256 * 2);
  u16* hu1B   = (u16*)alloc((size_t)NE * 256 * 2);
  u16* foB    = (u16*)alloc((size_t)NN * 256 * 2);
  int* bgm    = (int*)alloc((size_t)TT * NE * 6 * 4);
  int* agm    = (int*)alloc((size_t)TT * NN * 6 * 4);
  float* gvec = (float*)alloc((size_t)TT * BATCH * 256 * 4);
  u16* Wh_t   = (u16*)alloc(256 * 256 * 2);
  u16* Uh_t   = (u16*)alloc(256 * 256 * 2);
  u16* Wo1_t  = (u16*)alloc(256 * 256 * 2);
  u16* Wo2_t  = (u16*)alloc(256 * 256 * 2);
  u16* tw1_t  = (u16*)alloc(256 * 544 * 2);
  u16* aw1_t  = (u16*)alloc(256 * 544 * 2);
  u16* bw1_t  = (u16*)alloc(256 * 800 * 2);
  u16* rw_t   = (u16*)alloc(256 * 320 * 2);
  u16* ww_t   = (u16*)alloc(256 * 288 * 2);
  u16* tva    = (u16*)alloc((size_t)(PT + PA) * 544 * 2);
  u16* bv     = (u16*)alloc((size_t)PB * 800 * 2);
  u16* wbin   = (u16*)alloc((size_t)PB * 288 * 2);
  u16* rbin   = (u16*)alloc((size_t)PB * 320 * 2);
  u16* wb     = (u16*)alloc((size_t)PB * 256 * 2);
  u16* ha_hid = (u16*)alloc((size_t)(PT + PA) * 256 * 2);
  u16* b_hid  = (u16*)alloc((size_t)PB * 256 * 2);
  u16* tv     = tva;
  u16* av     = tva + (size_t)PT * 544;
  u16* t_hid  = ha_hid;
  u16* a_hid  = ha_hid + (size_t)PT * 256;

  // chunked buffers: pick largest TB in {6,3,2,1} that fits
  size_t used = (size_t)(wp - (char*)d_ws);
  size_t per_tb = ((size_t)NE * 256 * 2) * 2 + (size_t)NN * 256 * 2 + 3 * 256;
  size_t remain = (ws_size > used) ? (ws_size - used) : 0;
  int TB = 1;
  if (6 * per_tb <= remain) TB = 6;
  else if (3 * per_tb <= remain) TB = 3;
  else if (2 * per_tb <= remain) TB = 2;
  u16* T1    = (u16*)alloc((size_t)TB * NE * 256 * 2);
  u16* T2    = (u16*)alloc((size_t)TB * NE * 256 * 2);
  u16* nodeB = (u16*)alloc((size_t)TB * NN * 256 * 2);

  float* out = (float*)d_out;
  hipMemsetAsync(out, 0, sizeof(float), stream);
  hipMemsetAsync(gvec, 0, (size_t)TT * BATCH * 256 * 4, stream);

#define GEMM(relu, af32, Aptr, lda, M, Btptr, K, Cptr, ldc, biasptr)                          \
  do { dim3 g_(((M) + 127) / 128, 2);                                                         \
    gemm_bt_kernel<relu, af32><<<g_, 256, 0, stream>>>((const void*)(Aptr), (lda), (M),       \
                                                       (Btptr), (K), (Cptr), (ldc), (biasptr)); \
  } while (0)

  // weight transposes (one dispatch)
  transpose_all_kernel<<<3520, 256, 0, stream>>>(W_h, U_h, W_o, topo_w1, atom_w1, bond_w1,
      rbond_w, wbond_w, Wh_t, Uh_t, Wo1_t, Wo2_t, tw1_t, aw1_t, bw1_t, rw_t, ww_t);

  // masked neighbor lists for all steps (one dispatch)
  mask_kernel<<<dim3(2111, TT), 256, 0, stream>>>(bgraph, agraph, emask, bgm, agm);

  // step-invariant precomputes (GEMMs read f32 inputs directly)
  GEMM(0, 1, fmess, 256, NE, Wh_t, 256, preB, 256, nullptr);     // pre = fmess @ W_h
  GEMM(0, 1, fnode, 256, NN, Wo1_t, 256, foB, 256, nullptr);     // fo  = fnode @ W_o[:256]
  h1_kernel<<<15000, 256, 0, stream>>>(preB, b_h, T1);           // h1 -> T1
  GEMM(0, 0, T1, 256, NE, Uh_t, 256, hu1B, 256, nullptr);        // hu1 = h1 @ U_h

  for (int t0 = 0; t0 < TT; t0 += TB) {
    const int* bgm_c = bgm + (size_t)t0 * NE * 6;
    const int* agm_c = agm + (size_t)t0 * NN * 6;
    int Mtot = TB * NE;
    int fb = (Mtot + 127) / 128;
    // depth 2: T1 = relu(pre + gather(hu1) + b_h)*pad @ U_h   (hu1 shared across t)
    fused_gg_kernel<<<fb, 512, 0, stream>>>(hu1B, 0, preB, b_h, bgm_c, Mtot, Uh_t, T1);
    // depth 3: T2 = A(T1) @ U_h
    fused_gg_kernel<<<fb, 512, 0, stream>>>(T1, NE, preB, b_h, bgm_c, Mtot, Uh_t, T2);
    // depth 4: T1 = A(T2) @ W_o[256:]
    fused_gg_kernel<<<fb, 512, 0, stream>>>(T2, NE, preB, b_h, bgm_c, Mtot, Wo2_t, T1);
    // node = relu(fo + gather(T1) + b_o) * vm
    gather_n2_kernel<<<TB * (NN / 8), 256, 0, stream>>>(T1, (long)NE * 256, foB, b_o, agm_c,
                                                        vmask + (size_t)t0 * NN, nodeB);
    // graph vectors (atomic segmented reduction)
    gvec_atomic_kernel<<<dim3(938, TB), 256, 0, stream>>>(nodeB, node2graph, gvec, t0);
    // scatter node rows into head inputs
    head_gather_kernel<<<1344, 256, 0, stream>>>(t0, TB, nodeB,
        topo_step, topo_xid, atom_step, atom_xid, bond_step, bond_zid,
        tv, av, bv, wbin);
  }

  // static head-input segments
  build_static_kernel<<<1344, 256, 0, stream>>>(gvec, src,
      topo_step, topo_bid, atom_step, atom_bid, bond_step, bond_bid,
      bond_label, bond_atype, tv, av, bv, wbin, rbin);

  // heads: merged topo+atom GEMM, then bond chain
  gemm_ta_kernel<<<dim3((PT + PA) / 128, 2), 256, 0, stream>>>(tva, tw1_t, aw1_t,
                                                               topo_b1, atom_b1, ha_hid);
  GEMM(1, 0, wbin, 288, PB, ww_t, 288, wb, 256, wbond_b);
  hist_kernel<<<640, 256, 0, stream>>>(wb, bond_gs, bond_label, rbin);
  GEMM(1, 0, rbin, 320, PB, rw_t, 320, bv + 256, 800, rbond_b);  // cur -> bv[:,256:512]
  GEMM(1, 0, bv, 800, PB, bw1_t, 800, b_hid, 256, bond_b1);

  // losses
  topo_loss_kernel<<<384, 256, 0, stream>>>(t_hid, topo_w2, topo_b2, topo_label, out);
  ce_loss_kernel<VV><<<320, 256, 0, stream>>>(a_hid, atom_w2, atom_b2, atom_label, PA, out);
  ce_loss_kernel<NBOND><<<640, 256, 0, stream>>>(b_hid, bond_w2, bond_b2, bond_label, PB, out);

#undef GEMM
}